// Round 14
// baseline (41.004 us; speedup 1.0000x reference)
//
#include <hip/hip_runtime.h>

typedef short s8v __attribute__((ext_vector_type(8)));
typedef float f4v __attribute__((ext_vector_type(4)));
typedef float f16v __attribute__((ext_vector_type(16)));

#define ND 4096
#define NMASK 4095

__device__ __forceinline__ unsigned short f2bf(float f) {
  __bf16 h = (__bf16)f;
  return __builtin_bit_cast(unsigned short, h);
}

__device__ __forceinline__ void gload_lds16(const void* g, void* l) {
  __builtin_amdgcn_global_load_lds(
      (const __attribute__((address_space(1))) unsigned int*)g,
      (__attribute__((address_space(3))) unsigned int*)l, 16, 0, 0);
}

// Fused prep:
//  blocks [0,1024):  X f32 -> bf16 in OCTET-MAJOR layout
//                    Xpk[(oct*1024 + row)*8 + j] = bf16(X[row][oct*8+j])
//  blocks [1024,1088): 8-fold sliding-window W table:
//                    wlg[8s+t] = bf16(W[(s+t)&4095])
__global__ __launch_bounds__(256)
void prep(const float* __restrict__ X, const float* __restrict__ W,
          unsigned short* __restrict__ Xpk, unsigned int* __restrict__ wlg) {
  const int b = blockIdx.x;
  const int tid = threadIdx.x;
  if (b < 1024) {
    const int r0 = (b & 15) << 6;        // 64-row band
    const int k0 = (b >> 4) << 6;        // 64-k band
    const int r = tid >> 2;
    const int kseg = tid & 3;            // 16 k each
    const int row = r0 + r;
    const int k = k0 + (kseg << 4);
    const float* src = X + row * ND + k;
    const f4v g0 = *(const f4v*)(src + 0);
    const f4v g1 = *(const f4v*)(src + 4);
    const f4v g2 = *(const f4v*)(src + 8);
    const f4v g3 = *(const f4v*)(src + 12);
    s8v u0, u1;
    #pragma unroll
    for (int j = 0; j < 4; ++j) {
      u0[j] = (short)f2bf(g0[j]); u0[4 + j] = (short)f2bf(g1[j]);
      u1[j] = (short)f2bf(g2[j]); u1[4 + j] = (short)f2bf(g3[j]);
    }
    const int o0 = k >> 3;
    *(s8v*)(Xpk + ((o0 * 1024 + row) << 3))       = u0;
    *(s8v*)(Xpk + (((o0 + 1) * 1024 + row) << 3)) = u1;
  } else {
    const int m = (b - 1024) * 256 + tid;   // uint slot 0..16383
    const int e0 = m << 1, e1 = e0 + 1;
    const int i0 = ((e0 >> 3) + (e0 & 7)) & NMASK;
    const int i1 = ((e1 >> 3) + (e1 & 7)) & NMASK;
    wlg[m] = (unsigned int)f2bf(W[i0]) | ((unsigned int)f2bf(W[i1]) << 16);
  }
}

// BM=64, BN=256, BK=64. 512 threads = 8 waves = 2 wn-bands x 4 kb; grid =
// 256 = 1 block/CU single pass. Wave (wn,kb): 64x128 (2x4 frags 32x32x16)
// over K-quarter kb.
// ANTI-CONVOY: wave wv STARTS ITS K-WALK AT TILE tt0 = 8*wv and wraps
// (K-sum is order-independent). Waves are then 8 tiles apart at all times:
// at any instant ~1 wave is in its LDS-read phase, ~2 in MFMA, ~1 issuing
// A-loads -> the matrix/LDS/L1 pipes overlap instead of serializing (the
// measured 1310cy/tile period == the SERIAL SUM of pipe demands; parallel
// max is ~512). The circulant B index (base + 64*tt) mod 4096 makes the
// stagger free for B: only the initial s values change, the incremental
// +64 & 4095 update wraps across tt=63->0 seamlessly.
// MAIN LOOP: fully unrolled, no barriers, no LDS writes; A depth-2 (3-buf),
// B depth-1 (2-buf); setprio around MFMA cluster (waves now phase-diverse).
// EPILOGUE: per wn-group 4-way positional reduction; every wave stores a
// quarter (3 barriers).
__global__ __launch_bounds__(512, 2)
void circ_mm(const unsigned short* __restrict__ Xpk,
             const unsigned short* __restrict__ wlg,
             const float* __restrict__ bias, float* __restrict__ C) {
  extern __shared__ unsigned short smem[];
  unsigned char* __restrict__ sb = (unsigned char*)smem;   // wl: first 64 KB

  const int tid = threadIdx.x;
  const int bid = blockIdx.x;
  // XCD-aware mapping: XCD x serves m-tiles {x, x+8}; 16 n-tiles share the
  // Xpk panel in that XCD's L2.
  const int x = bid & 7;
  const int i = bid >> 3;               // 0..31
  const int m0 = (x + ((i >> 4) << 3)) << 6;   // 16 m-tiles of 64 rows
  const int n0 = (i & 15) << 8;                // 16 n-tiles of 256 cols

  const int lane = tid & 63;
  const int wv = tid >> 6;          // 0..7
  const int kb = wv & 3;            // K-quarter (k16 of each 64-k tile)
  const int wn = wv >> 2;           // 128-col band
  const int tt0 = wv << 3;          // staggered K-walk start tile

  // ---- async copy wl -> LDS (64 KB = 8 iters x 8 waves x 1 KB) ----
  #pragma unroll
  for (int it = 0; it < 8; ++it) {
    const int b = it * 8192 + (wv << 10);              // wave-uniform base
    gload_lds16((const unsigned char*)wlg + b + lane * 16, sb + b);
  }

  // ---- fragment geometry (mfma_f32_32x32x16_bf16) ----
  const int lc = lane & 31;
  const int lh = lane >> 5;
  const int lh8 = lh << 3;

  // A source: lane reads (row = m0 + mf*32 + lc, oct = tt*8 + kb*2 + lh).
  const unsigned short* gXa =
      Xpk + ((((kb << 1) + lh) << 10) + m0 + lc) * 8;

  // B window indices (one per n-frag), staggered start, +64/tile with wrap.
  int s0 = ((kb << 4) + lh8 - (n0 + wn * 128 + 0 * 32 + lc) + (tt0 << 6)) & NMASK;
  int s1 = ((kb << 4) + lh8 - (n0 + wn * 128 + 1 * 32 + lc) + (tt0 << 6)) & NMASK;
  int s2 = ((kb << 4) + lh8 - (n0 + wn * 128 + 2 * 32 + lc) + (tt0 << 6)) & NMASK;
  int s3 = ((kb << 4) + lh8 - (n0 + wn * 128 + 3 * 32 + lc) + (tt0 << 6)) & NMASK;

  f16v acc[2][4];
  #pragma unroll
  for (int mf = 0; mf < 2; ++mf)
    #pragma unroll
    for (int nf = 0; nf < 4; ++nf)
      #pragma unroll
      for (int e = 0; e < 16; ++e) acc[mf][nf][e] = 0.f;

  s8v Ab[3][2];                     // 3-buffer A rotation (depth-2)
  s8v Bb[2][4];                     // 2-buffer B rotation (depth-1)

  // ---- prologue: issue A(tt0),A(tt0+1); wl resident; read B(tt0) ----
  // tt0 <= 56, so tt0+1 never wraps.
  Ab[0][0] = *(const s8v*)(gXa + tt0 * 65536);
  Ab[0][1] = *(const s8v*)(gXa + tt0 * 65536 + 256);
  Ab[1][0] = *(const s8v*)(gXa + (tt0 + 1) * 65536);
  Ab[1][1] = *(const s8v*)(gXa + (tt0 + 1) * 65536 + 256);
  __syncthreads();                  // wl resident (drains vmcnt incl. A loads)
  Bb[0][0] = *(const s8v*)(sb + (s0 << 4));
  Bb[0][1] = *(const s8v*)(sb + (s1 << 4));
  Bb[0][2] = *(const s8v*)(sb + (s2 << 4));
  Bb[0][3] = *(const s8v*)(sb + (s3 << 4));

  // ---- main loop: fully unrolled; wave-local tile tt = (tt0 + t) & 63 ----
  #pragma unroll
  for (int t = 0; t < 64; ++t) {
    if (t + 2 < 64) {               // compile-time condition
      const int tt2 = (tt0 + t + 2) & 63;      // wave-uniform, SALU-cheap
      const unsigned short* gp = gXa + tt2 * 65536;
      Ab[(t + 2) % 3][0] = *(const s8v*)(gp + 0);
      Ab[(t + 2) % 3][1] = *(const s8v*)(gp + 256);
    }
    if (t + 1 < 64) {               // compile-time condition
      s0 = (s0 + 64) & NMASK;
      s1 = (s1 + 64) & NMASK;
      s2 = (s2 + 64) & NMASK;
      s3 = (s3 + 64) & NMASK;
      Bb[(t + 1) & 1][0] = *(const s8v*)(sb + (s0 << 4));
      Bb[(t + 1) & 1][1] = *(const s8v*)(sb + (s1 << 4));
      Bb[(t + 1) & 1][2] = *(const s8v*)(sb + (s2 << 4));
      Bb[(t + 1) & 1][3] = *(const s8v*)(sb + (s3 << 4));
    }

    const s8v a0 = Ab[t % 3][0];
    const s8v a1 = Ab[t % 3][1];
    __builtin_amdgcn_s_setprio(1);
    acc[0][0] = __builtin_amdgcn_mfma_f32_32x32x16_bf16(a0, Bb[t & 1][0], acc[0][0], 0, 0, 0);
    acc[1][0] = __builtin_amdgcn_mfma_f32_32x32x16_bf16(a1, Bb[t & 1][0], acc[1][0], 0, 0, 0);
    acc[0][1] = __builtin_amdgcn_mfma_f32_32x32x16_bf16(a0, Bb[t & 1][1], acc[0][1], 0, 0, 0);
    acc[1][1] = __builtin_amdgcn_mfma_f32_32x32x16_bf16(a1, Bb[t & 1][1], acc[1][1], 0, 0, 0);
    acc[0][2] = __builtin_amdgcn_mfma_f32_32x32x16_bf16(a0, Bb[t & 1][2], acc[0][2], 0, 0, 0);
    acc[1][2] = __builtin_amdgcn_mfma_f32_32x32x16_bf16(a1, Bb[t & 1][2], acc[1][2], 0, 0, 0);
    acc[0][3] = __builtin_amdgcn_mfma_f32_32x32x16_bf16(a0, Bb[t & 1][3], acc[0][3], 0, 0, 0);
    acc[1][3] = __builtin_amdgcn_mfma_f32_32x32x16_bf16(a1, Bb[t & 1][3], acc[1][3], 0, 0, 0);
    __builtin_amdgcn_s_setprio(0);
  }

  // ---- epilogue: per wn-group 4-way positional reduction, 3 barriers ----
  // chunk j = (mf*4+nf)*4+q, j in [0,32); element access by VALUE.
  #define ACC_EL(j, e) (acc[(j) >> 4][((j) >> 2) & 3][((j) & 3) * 4 + (e)])

  __syncthreads();                  // main-loop wl reads done (overlays wl)
  float* gbase = (float*)smem + wn * 16384;   // 64 KB per wn-group
  // band0 = gbase[0..8192), band1 = gbase[8192..16384)

  // step 1: kb2/kb3 dump full acc; then kb0/kb1 accumulate + publish
  if (kb == 2 || kb == 3) {
    float* rb = gbase + (kb - 2) * 8192;
    #pragma unroll
    for (int j = 0; j < 32; ++j) {
      f4v v;
      #pragma unroll
      for (int e = 0; e < 4; ++e) v[e] = ACC_EL(j, e);
      *(f4v*)(&rb[(j * 64 + lane) * 4]) = v;
    }
  }
  __syncthreads();
  if (kb == 0) {
    float* rb = gbase;              // band0: sum02 = acc + kb2
    #pragma unroll
    for (int j = 0; j < 32; ++j) {
      const f4v v = *(const f4v*)(&rb[(j * 64 + lane) * 4]);
      #pragma unroll
      for (int e = 0; e < 4; ++e) ACC_EL(j, e) += v[e];
    }
    #pragma unroll
    for (int j = 8; j < 32; ++j) {  // publish chunks 8..31
      f4v v;
      #pragma unroll
      for (int e = 0; e < 4; ++e) v[e] = ACC_EL(j, e);
      *(f4v*)(&rb[(j * 64 + lane) * 4]) = v;
    }
  }
  if (kb == 1) {
    float* rb = gbase + 8192;       // band1: sum13 = acc + kb3
    #pragma unroll
    for (int j = 0; j < 32; ++j) {
      const f4v v = *(const f4v*)(&rb[(j * 64 + lane) * 4]);
      #pragma unroll
      for (int e = 0; e < 4; ++e) ACC_EL(j, e) += v[e];
    }
    #pragma unroll
    for (int j = 0; j < 8; ++j) {   // publish chunks 0..7
      f4v v;
      #pragma unroll
      for (int e = 0; e < 4; ++e) v[e] = ACC_EL(j, e);
      *(f4v*)(&rb[(j * 64 + lane) * 4]) = v;
    }
    #pragma unroll
    for (int j = 16; j < 32; ++j) { // publish chunks 16..31
      f4v v;
      #pragma unroll
      for (int e = 0; e < 4; ++e) v[e] = ACC_EL(j, e);
      *(f4v*)(&rb[(j * 64 + lane) * 4]) = v;
    }
  }
  __syncthreads();

  // final: wave (wn,kb) sums its quarter (chunks 8*kb .. 8*kb+8) and stores
  {
    const int lh4 = lh << 2;
    const int nfb = (kb & 1) * 2;   // quarter spans nf in {nfb, nfb+1}
    float bv[2];
    bv[0] = bias[n0 + wn * 128 + (nfb + 0) * 32 + lc];
    bv[1] = bias[n0 + wn * 128 + (nfb + 1) * 32 + lc];

    #pragma unroll
    for (int jj = 0; jj < 8; ++jj) {
      f4v v;
      if (kb == 0) {                // j = jj: regs(sum02) + band1(sum13)
        const int j = jj;
        const f4v w = *(const f4v*)(&gbase[8192 + (j * 64 + lane) * 4]);
        #pragma unroll
        for (int e = 0; e < 4; ++e) v[e] = ACC_EL(j, e) + w[e];
      } else if (kb == 1) {         // j = 8+jj: regs(sum13) + band0(sum02)
        const int j = 8 + jj;
        const f4v w = *(const f4v*)(&gbase[(j * 64 + lane) * 4]);
        #pragma unroll
        for (int e = 0; e < 4; ++e) v[e] = ACC_EL(j, e) + w[e];
      } else {                      // j = 8*kb+jj: band0 + band1
        const int j = kb * 8 + jj;
        const f4v w0 = *(const f4v*)(&gbase[(j * 64 + lane) * 4]);
        const f4v w1 = *(const f4v*)(&gbase[8192 + (j * 64 + lane) * 4]);
        #pragma unroll
        for (int e = 0; e < 4; ++e) v[e] = w0[e] + w1[e];
      }
      const int j = kb * 8 + jj;
      const int mf = j >> 4;
      const int nf = (j >> 2) & 3;
      const int q  = j & 3;
      const int col = n0 + wn * 128 + nf * 32 + lc;
      const int row = m0 + mf * 32 + q * 8 + lh4;
      const float b = bv[nf - nfb];
      #pragma unroll
      for (int e = 0; e < 4; ++e)
        C[(row + e) * ND + col] = v[e] + b;
    }
  }
  #undef ACC_EL
}

extern "C" void kernel_launch(void* const* d_in, const int* in_sizes, int n_in,
                              void* d_out, int out_size, void* d_ws, size_t ws_size,
                              hipStream_t stream) {
  (void)hipFuncSetAttribute((const void*)circ_mm,
                            hipFuncAttributeMaxDynamicSharedMemorySize, 131072);
  const float* X    = (const float*)d_in[0];
  const float* W    = (const float*)d_in[1];
  const float* bias = (const float*)d_in[2];
  unsigned short* wlg = (unsigned short*)d_ws;            // 64 KB table
  unsigned short* Xpk = (unsigned short*)d_ws + 32768;    // 8 MB octet-major X

  prep<<<dim3(1088), dim3(256), 0, stream>>>(X, W, Xpk, (unsigned int*)wlg);
  circ_mm<<<dim3(256), dim3(512), 131072, stream>>>(Xpk, wlg, bias, (float*)d_out);
}

// Round 15
// 38.264 us; speedup vs baseline: 1.0716x; 1.0716x over previous
//
#include <hip/hip_runtime.h>

typedef short s8v __attribute__((ext_vector_type(8)));
typedef float f4v __attribute__((ext_vector_type(4)));
typedef float f16v __attribute__((ext_vector_type(16)));

#define ND 4096
#define NMASK 4095

__device__ __forceinline__ unsigned short f2bf(float f) {
  __bf16 h = (__bf16)f;
  return __builtin_bit_cast(unsigned short, h);
}

__device__ __forceinline__ void gload_lds16(const void* g, void* l) {
  __builtin_amdgcn_global_load_lds(
      (const __attribute__((address_space(1))) unsigned int*)g,
      (__attribute__((address_space(3))) unsigned int*)l, 16, 0, 0);
}

// Fused prep:
//  blocks [0,1024):  X f32 -> bf16 in OCTET-MAJOR layout
//                    Xpk[(oct*1024 + row)*8 + j] = bf16(X[row][oct*8+j])
//  blocks [1024,1088): 8-fold sliding-window W table:
//                    wlg[8s+t] = bf16(W[(s+t)&4095])
__global__ __launch_bounds__(256)
void prep(const float* __restrict__ X, const float* __restrict__ W,
          unsigned short* __restrict__ Xpk, unsigned int* __restrict__ wlg) {
  const int b = blockIdx.x;
  const int tid = threadIdx.x;
  if (b < 1024) {
    const int r0 = (b & 15) << 6;        // 64-row band
    const int k0 = (b >> 4) << 6;        // 64-k band
    const int r = tid >> 2;
    const int kseg = tid & 3;            // 16 k each
    const int row = r0 + r;
    const int k = k0 + (kseg << 4);
    const float* src = X + row * ND + k;
    const f4v g0 = *(const f4v*)(src + 0);
    const f4v g1 = *(const f4v*)(src + 4);
    const f4v g2 = *(const f4v*)(src + 8);
    const f4v g3 = *(const f4v*)(src + 12);
    s8v u0, u1;
    #pragma unroll
    for (int j = 0; j < 4; ++j) {
      u0[j] = (short)f2bf(g0[j]); u0[4 + j] = (short)f2bf(g1[j]);
      u1[j] = (short)f2bf(g2[j]); u1[4 + j] = (short)f2bf(g3[j]);
    }
    const int o0 = k >> 3;
    *(s8v*)(Xpk + ((o0 * 1024 + row) << 3))       = u0;
    *(s8v*)(Xpk + (((o0 + 1) * 1024 + row) << 3)) = u1;
  } else {
    const int m = (b - 1024) * 256 + tid;   // uint slot 0..16383
    const int e0 = m << 1, e1 = e0 + 1;
    const int i0 = ((e0 >> 3) + (e0 & 7)) & NMASK;
    const int i1 = ((e1 >> 3) + (e1 & 7)) & NMASK;
    wlg[m] = (unsigned int)f2bf(W[i0]) | ((unsigned int)f2bf(W[i1]) << 16);
  }
}

// BM=64, BN=256, BK=64. 512 threads = 8 waves = 2 wn-bands x 4 kb; grid =
// 256 = 1 block/CU single pass. Wave (wn,kb): 64x128 (2x4 frags 32x32x16)
// over K-quarter kb.
// CIRCULANT B-FRAGMENT REUSE: the B window index is
//   s(nf,t) = base - 32*nf + 64*t (mod 4096)  =>  s(nf+2, t+1) = s(nf, t),
// so next tile's fragments 2,3 ARE this tile's fragments 0,1. Per tile a
// wave reads only 2 fresh B fragments (was 4); the other two rotate in
// registers (free under full unroll). Block LDS traffic halves
// (32 -> 16 ds_read_b128 per CU-tile), VALU index updates halve.
// MAIN LOOP: fully unrolled, no barriers, no LDS writes; A depth-2 (3-buf)
// via coalesced global loads from octet-major Xpk; B depth-1 fresh pair;
// setprio around the MFMA cluster.
// EPILOGUE: per wn-group 4-way positional reduction; every wave stores a
// quarter (3 barriers).
__global__ __launch_bounds__(512, 2)
void circ_mm(const unsigned short* __restrict__ Xpk,
             const unsigned short* __restrict__ wlg,
             const float* __restrict__ bias, float* __restrict__ C) {
  extern __shared__ unsigned short smem[];
  unsigned char* __restrict__ sb = (unsigned char*)smem;   // wl: first 64 KB

  const int tid = threadIdx.x;
  const int bid = blockIdx.x;
  // XCD-aware mapping: XCD x serves m-tiles {x, x+8}; 16 n-tiles share the
  // Xpk panel in that XCD's L2.
  const int x = bid & 7;
  const int i = bid >> 3;               // 0..31
  const int m0 = (x + ((i >> 4) << 3)) << 6;   // 16 m-tiles of 64 rows
  const int n0 = (i & 15) << 8;                // 16 n-tiles of 256 cols

  const int lane = tid & 63;
  const int wv = tid >> 6;          // 0..7
  const int kb = wv & 3;            // K-quarter (k16 of each 64-k tile)
  const int wn = wv >> 2;           // 128-col band

  // ---- async copy wl -> LDS (64 KB = 8 iters x 8 waves x 1 KB) ----
  #pragma unroll
  for (int it = 0; it < 8; ++it) {
    const int b = it * 8192 + (wv << 10);              // wave-uniform base
    gload_lds16((const unsigned char*)wlg + b + lane * 16, sb + b);
  }

  // ---- fragment geometry (mfma_f32_32x32x16_bf16) ----
  const int lc = lane & 31;
  const int lh = lane >> 5;
  const int lh8 = lh << 3;

  // A source: lane reads (row = m0 + mf*32 + lc, oct = t*8 + kb*2 + lh).
  const unsigned short* gXa =
      Xpk + ((((kb << 1) + lh) << 10) + m0 + lc) * 8;

  // B window indices: only nf=0,1 tracked (+64/tile); nf=2,3 come from
  // register rotation. Initial fragments also need s0-64, s1-64.
  int s0 = ((kb << 4) + lh8 - (n0 + wn * 128 + 0 * 32 + lc)) & NMASK;
  int s1 = ((kb << 4) + lh8 - (n0 + wn * 128 + 1 * 32 + lc)) & NMASK;

  f16v acc[2][4];
  #pragma unroll
  for (int mf = 0; mf < 2; ++mf)
    #pragma unroll
    for (int nf = 0; nf < 4; ++nf)
      #pragma unroll
      for (int e = 0; e < 16; ++e) acc[mf][nf][e] = 0.f;

  s8v Ab[3][2];                     // 3-buffer A rotation (depth-2)
  s8v B0, B1, B2, B3;               // current-tile B fragments (nf=0..3)
  s8v Bn0, Bn1;                     // fresh pair for tile t+1

  // ---- prologue: issue A(0),A(1); wl resident; read B frags of tile 0 ----
  Ab[0][0] = *(const s8v*)(gXa + 0);
  Ab[0][1] = *(const s8v*)(gXa + 256);
  Ab[1][0] = *(const s8v*)(gXa + 65536);
  Ab[1][1] = *(const s8v*)(gXa + 65536 + 256);
  __syncthreads();                  // wl resident (drains vmcnt incl. A loads)
  {
    const int s2 = (s0 - 64) & NMASK;   // s(2,0) = s(0,0) - 64
    const int s3 = (s1 - 64) & NMASK;   // s(3,0) = s(1,0) - 64
    B0 = *(const s8v*)(sb + (s0 << 4));
    B1 = *(const s8v*)(sb + (s1 << 4));
    B2 = *(const s8v*)(sb + (s2 << 4));
    B3 = *(const s8v*)(sb + (s3 << 4));
  }

  // ---- main loop: fully unrolled; 2 fresh B reads/tile + rotation ----
  #pragma unroll
  for (int t = 0; t < 64; ++t) {
    if (t + 2 < 64) {               // compile-time condition
      const unsigned short* gp = gXa + (t + 2) * 65536;
      Ab[(t + 2) % 3][0] = *(const s8v*)(gp + 0);
      Ab[(t + 2) % 3][1] = *(const s8v*)(gp + 256);
    }
    if (t + 1 < 64) {               // compile-time condition
      s0 = (s0 + 64) & NMASK;       // s(0, t+1)
      s1 = (s1 + 64) & NMASK;       // s(1, t+1)
      Bn0 = *(const s8v*)(sb + (s0 << 4));
      Bn1 = *(const s8v*)(sb + (s1 << 4));
    }

    const s8v a0 = Ab[t % 3][0];
    const s8v a1 = Ab[t % 3][1];
    __builtin_amdgcn_s_setprio(1);
    acc[0][0] = __builtin_amdgcn_mfma_f32_32x32x16_bf16(a0, B0, acc[0][0], 0, 0, 0);
    acc[1][0] = __builtin_amdgcn_mfma_f32_32x32x16_bf16(a1, B0, acc[1][0], 0, 0, 0);
    acc[0][1] = __builtin_amdgcn_mfma_f32_32x32x16_bf16(a0, B1, acc[0][1], 0, 0, 0);
    acc[1][1] = __builtin_amdgcn_mfma_f32_32x32x16_bf16(a1, B1, acc[1][1], 0, 0, 0);
    acc[0][2] = __builtin_amdgcn_mfma_f32_32x32x16_bf16(a0, B2, acc[0][2], 0, 0, 0);
    acc[1][2] = __builtin_amdgcn_mfma_f32_32x32x16_bf16(a1, B2, acc[1][2], 0, 0, 0);
    acc[0][3] = __builtin_amdgcn_mfma_f32_32x32x16_bf16(a0, B3, acc[0][3], 0, 0, 0);
    acc[1][3] = __builtin_amdgcn_mfma_f32_32x32x16_bf16(a1, B3, acc[1][3], 0, 0, 0);
    __builtin_amdgcn_s_setprio(0);

    // rotate: next tile's frags 2,3 are this tile's 0,1; 0,1 are fresh.
    B2 = B0; B3 = B1; B0 = Bn0; B1 = Bn1;
  }

  // ---- epilogue: per wn-group 4-way positional reduction, 3 barriers ----
  // chunk j = (mf*4+nf)*4+q, j in [0,32); element access by VALUE.
  #define ACC_EL(j, e) (acc[(j) >> 4][((j) >> 2) & 3][((j) & 3) * 4 + (e)])

  __syncthreads();                  // main-loop wl reads done (overlays wl)
  float* gbase = (float*)smem + wn * 16384;   // 64 KB per wn-group
  // band0 = gbase[0..8192), band1 = gbase[8192..16384)

  // step 1: kb2/kb3 dump full acc; then kb0/kb1 accumulate + publish
  if (kb == 2 || kb == 3) {
    float* rb = gbase + (kb - 2) * 8192;
    #pragma unroll
    for (int j = 0; j < 32; ++j) {
      f4v v;
      #pragma unroll
      for (int e = 0; e < 4; ++e) v[e] = ACC_EL(j, e);
      *(f4v*)(&rb[(j * 64 + lane) * 4]) = v;
    }
  }
  __syncthreads();
  if (kb == 0) {
    float* rb = gbase;              // band0: sum02 = acc + kb2
    #pragma unroll
    for (int j = 0; j < 32; ++j) {
      const f4v v = *(const f4v*)(&rb[(j * 64 + lane) * 4]);
      #pragma unroll
      for (int e = 0; e < 4; ++e) ACC_EL(j, e) += v[e];
    }
    #pragma unroll
    for (int j = 8; j < 32; ++j) {  // publish chunks 8..31
      f4v v;
      #pragma unroll
      for (int e = 0; e < 4; ++e) v[e] = ACC_EL(j, e);
      *(f4v*)(&rb[(j * 64 + lane) * 4]) = v;
    }
  }
  if (kb == 1) {
    float* rb = gbase + 8192;       // band1: sum13 = acc + kb3
    #pragma unroll
    for (int j = 0; j < 32; ++j) {
      const f4v v = *(const f4v*)(&rb[(j * 64 + lane) * 4]);
      #pragma unroll
      for (int e = 0; e < 4; ++e) ACC_EL(j, e) += v[e];
    }
    #pragma unroll
    for (int j = 0; j < 8; ++j) {   // publish chunks 0..7
      f4v v;
      #pragma unroll
      for (int e = 0; e < 4; ++e) v[e] = ACC_EL(j, e);
      *(f4v*)(&rb[(j * 64 + lane) * 4]) = v;
    }
    #pragma unroll
    for (int j = 16; j < 32; ++j) { // publish chunks 16..31
      f4v v;
      #pragma unroll
      for (int e = 0; e < 4; ++e) v[e] = ACC_EL(j, e);
      *(f4v*)(&rb[(j * 64 + lane) * 4]) = v;
    }
  }
  __syncthreads();

  // final: wave (wn,kb) sums its quarter (chunks 8*kb .. 8*kb+8) and stores
  {
    const int lh4 = lh << 2;
    const int nfb = (kb & 1) * 2;   // quarter spans nf in {nfb, nfb+1}
    float bv[2];
    bv[0] = bias[n0 + wn * 128 + (nfb + 0) * 32 + lc];
    bv[1] = bias[n0 + wn * 128 + (nfb + 1) * 32 + lc];

    #pragma unroll
    for (int jj = 0; jj < 8; ++jj) {
      f4v v;
      if (kb == 0) {                // j = jj: regs(sum02) + band1(sum13)
        const int j = jj;
        const f4v w = *(const f4v*)(&gbase[8192 + (j * 64 + lane) * 4]);
        #pragma unroll
        for (int e = 0; e < 4; ++e) v[e] = ACC_EL(j, e) + w[e];
      } else if (kb == 1) {         // j = 8+jj: regs(sum13) + band0(sum02)
        const int j = 8 + jj;
        const f4v w = *(const f4v*)(&gbase[(j * 64 + lane) * 4]);
        #pragma unroll
        for (int e = 0; e < 4; ++e) v[e] = ACC_EL(j, e) + w[e];
      } else {                      // j = 8*kb+jj: band0 + band1
        const int j = kb * 8 + jj;
        const f4v w0 = *(const f4v*)(&gbase[(j * 64 + lane) * 4]);
        const f4v w1 = *(const f4v*)(&gbase[8192 + (j * 64 + lane) * 4]);
        #pragma unroll
        for (int e = 0; e < 4; ++e) v[e] = w0[e] + w1[e];
      }
      const int j = kb * 8 + jj;
      const int mf = j >> 4;
      const int nf = (j >> 2) & 3;
      const int q  = j & 3;
      const int col = n0 + wn * 128 + nf * 32 + lc;
      const int row = m0 + mf * 32 + q * 8 + lh4;
      const float b = bv[nf - nfb];
      #pragma unroll
      for (int e = 0; e < 4; ++e)
        C[(row + e) * ND + col] = v[e] + b;
    }
  }
  #undef ACC_EL
}

extern "C" void kernel_launch(void* const* d_in, const int* in_sizes, int n_in,
                              void* d_out, int out_size, void* d_ws, size_t ws_size,
                              hipStream_t stream) {
  (void)hipFuncSetAttribute((const void*)circ_mm,
                            hipFuncAttributeMaxDynamicSharedMemorySize, 131072);
  const float* X    = (const float*)d_in[0];
  const float* W    = (const float*)d_in[1];
  const float* bias = (const float*)d_in[2];
  unsigned short* wlg = (unsigned short*)d_ws;            // 64 KB table
  unsigned short* Xpk = (unsigned short*)d_ws + 32768;    // 8 MB octet-major X

  prep<<<dim3(1088), dim3(256), 0, stream>>>(X, W, Xpk, (unsigned int*)wlg);
  circ_mm<<<dim3(256), dim3(512), 131072, stream>>>(Xpk, wlg, bias, (float*)d_out);
}